// Round 5
// baseline (79.656 us; speedup 1.0000x reference)
//
#include <hip/hip_runtime.h>

#define NUM_CLASSES 80
#define A_NUM 120000
#define B_NUM 8
#define N_BOX 64

typedef float f4 __attribute__((ext_vector_type(4)));

// R5 = R2 (best: 60.7us) restructured store-first:
//   Phase 0: each wave immediately nt-stores its 20KB cls range as ZEROS
//            (94% of all output bytes, depends on nothing) -> write pipe
//            saturated from cycle 0, IoU VALU hides behind the drain.
//   Phase 1: stage 64 GT boxes (+areas, labels) in LDS; one barrier.
//   Phase 2: per-anchor argmax-IoU (IEEE div, contract off = numpy-exact).
//            s_waitcnt vmcnt(0) after the loop (phase-0 stores long drained,
//            ~free) guarantees WAW order for the fixups.
//   Phase 3: rare positive lanes overwrite ONE f4 with their one-hot; then
//            nt reg_target (f4) + anchor_state stores.
// This deletes the LDS transpose + 80 compares/thread of R2's phase 3.
__global__ __launch_bounds__(256, 4) void compute_targets_kernel(
    const float* __restrict__ annotations,  // (B, 64, 5)
    const float4* __restrict__ anchors4,    // (A, 4)
    float* __restrict__ out)                // cls | reg | states, concat flat
{
#pragma clang fp contract(off)
    __shared__ float4 sbox[N_BOX];
    __shared__ float  sarea[N_BOX];
    __shared__ int    slab[N_BOX];

    const int tid  = threadIdx.x;
    const int wv   = tid >> 6;
    const int lane = tid & 63;
    const int b    = blockIdx.y;
    const int a0   = blockIdx.x * 256;
    const int aw0  = a0 + wv * 64;   // wave's anchor base (A_NUM % 64 == 0)
    const int a    = a0 + tid;
    const bool wave_valid = (aw0 < A_NUM);

    // ---- Phase 0: zero-fill this wave's cls rows NOW (20 x 1KB nt stores).
    f4* const clsbase = (f4*)out + ((size_t)b * A_NUM + aw0) * 20;
    if (wave_valid) {
        const f4 z = {0.0f, 0.0f, 0.0f, 0.0f};
#pragma unroll
        for (int i = 0; i < 20; ++i)
            __builtin_nontemporal_store(z, &clsbase[i * 64 + lane]);
    }

    // ---- Phase 1: stage boxes (wave 0 only), barrier.
    if (tid < N_BOX) {
        const float* ann = annotations + ((size_t)b * N_BOX + tid) * 5;
        const float x0 = ann[0], y0 = ann[1], x1 = ann[2], y1 = ann[3];
        sbox[tid]  = make_float4(x0, y0, x1, y1);
        sarea[tid] = (x1 - x0) * (y1 - y0);   // same f32 ops as reference
        slab[tid]  = (int)ann[4];
    }
    __syncthreads();

    if (!wave_valid) return;

    // ---- Phase 2: argmax-IoU, numpy-exact.
    const float4 anc = anchors4[a];
    const float wa = anc.z - anc.x;
    const float ha = anc.w - anc.y;
    const float area_a = wa * ha;

    float best_iou = -1.0f;
    int   best_j   = 0;
#pragma unroll 8
    for (int j = 0; j < N_BOX; ++j) {
        const float4 bx = sbox[j];                    // LDS broadcast
        const float ltx = fmaxf(anc.x, bx.x);
        const float lty = fmaxf(anc.y, bx.y);
        const float rbx = fminf(anc.z, bx.z);
        const float rby = fminf(anc.w, bx.w);
        const float w = fmaxf(rbx - ltx, 0.0f);
        const float h = fmaxf(rby - lty, 0.0f);
        const float inter = w * h;
        const float uni   = (area_a + sarea[j]) - inter;  // contract(off): no fma
        // union >= max(area) >= 1 (wh in [1,257]) so fmax(uni,1e-8) == uni.
        const float iou   = inter / uni;                  // IEEE div, matches np
        if (iou > best_iou) { best_iou = iou; best_j = j; }  // first-max wins
    }

    // Phase-0 stores drained ~3K cycles ago: this wait is ~free, and it
    // guarantees the one-hot fixup below lands AFTER the zero store (WAW).
    asm volatile("s_waitcnt vmcnt(0)" ::: "memory");

    const bool positive = best_iou >= 0.5f;
    const bool ignore   = (best_iou > 0.4f) && !positive;
    const float state   = positive ? 1.0f : (ignore ? -1.0f : 0.0f);

    // ---- Phase 3a: rare divergent one-hot fixup (positives only).
    if (positive) {
        const int lab = slab[best_j];
        const int r   = lab & 3;
        f4 v;
        v.x = (r == 0) ? 1.0f : 0.0f;
        v.y = (r == 1) ? 1.0f : 0.0f;
        v.z = (r == 2) ? 1.0f : 0.0f;
        v.w = (r == 3) ? 1.0f : 0.0f;
        __builtin_nontemporal_store(v, &clsbase[lane * 20 + (lab >> 2)]);
    }

    // ---- Phase 3b: reg_target + anchor_state.
    const float4 gt = sbox[best_j];
    f4 reg;
    reg.x = ((gt.x - anc.x) / wa) / 0.2f;
    reg.y = ((gt.y - anc.y) / ha) / 0.2f;
    reg.z = ((gt.z - anc.z) / wa) / 0.2f;
    reg.w = ((gt.w - anc.w) / ha) / 0.2f;

    const size_t CLS = (size_t)B_NUM * A_NUM * NUM_CLASSES;
    const size_t REG = (size_t)B_NUM * A_NUM * 4;
    f4* regout = (f4*)(out + CLS);
    __builtin_nontemporal_store(reg, &regout[(size_t)b * A_NUM + a]);
    __builtin_nontemporal_store(state, &out[CLS + REG + (size_t)b * A_NUM + a]);
}

extern "C" void kernel_launch(void* const* d_in, const int* in_sizes, int n_in,
                              void* d_out, int out_size, void* d_ws, size_t ws_size,
                              hipStream_t stream) {
    const float*  annotations = (const float*)d_in[0];   // (8, 64, 5)
    const float4* anchors     = (const float4*)d_in[1];  // (120000, 4)
    float* out = (float*)d_out;

    dim3 grid((A_NUM + 255) / 256, B_NUM);
    compute_targets_kernel<<<grid, 256, 0, stream>>>(annotations, anchors, out);
}

// Round 6
// 78.329 us; speedup vs baseline: 1.0169x; 1.0169x over previous
//
#include <hip/hip_runtime.h>

#define NUM_CLASSES 80
#define A_NUM 120000
#define B_NUM 8
#define N_BOX 64

typedef float f4 __attribute__((ext_vector_type(4)));

// Two-kernel structure (R6):
//  K1: per wave, FIRST issue 20 nt zero-f4 stores covering its 64 anchors'
//      one-hot rows (94% of output bytes; write pipe saturated from t=0,
//      never touched again in this kernel -> NO vmcnt fence needed, fixing
//      R5's serialization). Then stage boxes in LDS, argmax-IoU (IEEE div,
//      contract off = numpy-exact), store reg_target + anchor_state (nt)
//      and a per-anchor int8 label (-1 or class) into d_ws.
//  K2: 960K threads; read label byte; positives scatter a single 1.0f into
//      their one-hot row. Dispatch boundary = the WAW fence, for free.
// Fallback: if ws_size < B*A bytes, run the proven fused R2-style kernel.

__global__ __launch_bounds__(256, 4) void targets_main_kernel(
    const float* __restrict__ annotations,  // (B, 64, 5)
    const float4* __restrict__ anchors4,    // (A, 4)
    float* __restrict__ out,                // cls | reg | states
    signed char* __restrict__ labels)       // (B*A) ws, or null for fused
{
#pragma clang fp contract(off)
    __shared__ float4 sbox[N_BOX];
    __shared__ float  sarea[N_BOX];
    __shared__ int    slab[N_BOX];
    __shared__ int    scls[256];   // used only in fused fallback path

    const int tid  = threadIdx.x;
    const int wv   = tid >> 6;
    const int lane = tid & 63;
    const int b    = blockIdx.y;
    const int a0   = blockIdx.x * 256;
    const int aw0  = a0 + wv * 64;   // wave's anchor base (A_NUM % 64 == 0)
    const int a    = a0 + tid;
    const bool wave_valid = (aw0 < A_NUM);
    const bool split = (labels != nullptr);

    f4* const clsbase = (f4*)out + ((size_t)b * A_NUM + aw0) * 20;

    // ---- K1 phase 0 (split path only): zero this wave's one-hot rows NOW.
    // These lines are never rewritten by this kernel -> fire-and-forget.
    if (split && wave_valid) {
        const f4 z = {0.0f, 0.0f, 0.0f, 0.0f};
#pragma unroll
        for (int i = 0; i < 20; ++i)
            __builtin_nontemporal_store(z, &clsbase[i * 64 + lane]);
    }

    // ---- stage boxes, barrier.
    if (tid < N_BOX) {
        const float* ann = annotations + ((size_t)b * N_BOX + tid) * 5;
        const float x0 = ann[0], y0 = ann[1], x1 = ann[2], y1 = ann[3];
        sbox[tid]  = make_float4(x0, y0, x1, y1);
        sarea[tid] = (x1 - x0) * (y1 - y0);   // same f32 ops as reference
        slab[tid]  = (int)ann[4];
    }
    __syncthreads();

    if (!wave_valid) return;

    // ---- argmax-IoU, numpy-exact.
    const float4 anc = anchors4[a];
    const float wa = anc.z - anc.x;
    const float ha = anc.w - anc.y;
    const float area_a = wa * ha;

    float best_iou = -1.0f;
    int   best_j   = 0;
#pragma unroll 8
    for (int j = 0; j < N_BOX; ++j) {
        const float4 bx = sbox[j];                    // LDS broadcast
        const float ltx = fmaxf(anc.x, bx.x);
        const float lty = fmaxf(anc.y, bx.y);
        const float rbx = fminf(anc.z, bx.z);
        const float rby = fminf(anc.w, bx.w);
        const float w = fmaxf(rbx - ltx, 0.0f);
        const float h = fmaxf(rby - lty, 0.0f);
        const float inter = w * h;
        const float uni   = (area_a + sarea[j]) - inter;  // contract(off): no fma
        // union >= max(area) >= 1 (wh in [1,257]) so fmax(uni,1e-8) == uni.
        const float iou   = inter / uni;                  // IEEE div, matches np
        if (iou > best_iou) { best_iou = iou; best_j = j; }  // first-max wins
    }

    const bool positive = best_iou >= 0.5f;
    const bool ignore   = (best_iou > 0.4f) && !positive;
    const float state   = positive ? 1.0f : (ignore ? -1.0f : 0.0f);

    const float4 gt = sbox[best_j];
    f4 reg;
    reg.x = ((gt.x - anc.x) / wa) / 0.2f;
    reg.y = ((gt.y - anc.y) / ha) / 0.2f;
    reg.z = ((gt.z - anc.z) / wa) / 0.2f;
    reg.w = ((gt.w - anc.w) / ha) / 0.2f;

    const size_t CLS = (size_t)B_NUM * A_NUM * NUM_CLASSES;
    const size_t REG = (size_t)B_NUM * A_NUM * 4;
    f4* regout = (f4*)(out + CLS);
    __builtin_nontemporal_store(reg, &regout[(size_t)b * A_NUM + a]);
    __builtin_nontemporal_store(state, &out[CLS + REG + (size_t)b * A_NUM + a]);

    if (split) {
        // compact label for kernel 2's sparse fixup
        labels[(size_t)b * A_NUM + a] = positive ? (signed char)slab[best_j] : (signed char)-1;
        return;
    }

    // ---- fused fallback (R2 phase 3): wave-local LDS transpose + one-hot.
    scls[tid] = positive ? slab[best_j] : -1;
#pragma unroll
    for (int i = 0; i < 20; ++i) {
        const int pos = i * 64 + lane;
        const int al  = pos / 20;
        const int q   = pos - al * 20;
        const int lab = scls[wv * 64 + al];
        const int c0  = q * 4;
        f4 v;
        v.x = (lab == c0    ) ? 1.0f : 0.0f;
        v.y = (lab == c0 + 1) ? 1.0f : 0.0f;
        v.z = (lab == c0 + 2) ? 1.0f : 0.0f;
        v.w = (lab == c0 + 3) ? 1.0f : 0.0f;
        __builtin_nontemporal_store(v, &clsbase[pos]);
    }
}

// K2: sparse one-hot fixup. 3750*256 == 960000 exactly.
__global__ __launch_bounds__(256) void targets_fixup_kernel(
    const signed char* __restrict__ labels,
    float* __restrict__ out)
{
    const int idx = blockIdx.x * 256 + threadIdx.x;   // = b*A + a
    const int lab = labels[idx];
    if (lab >= 0)
        out[(size_t)idx * NUM_CLASSES + lab] = 1.0f;
}

extern "C" void kernel_launch(void* const* d_in, const int* in_sizes, int n_in,
                              void* d_out, int out_size, void* d_ws, size_t ws_size,
                              hipStream_t stream) {
    const float*  annotations = (const float*)d_in[0];   // (8, 64, 5)
    const float4* anchors     = (const float4*)d_in[1];  // (120000, 4)
    float* out = (float*)d_out;

    const size_t need = (size_t)B_NUM * A_NUM;           // 960000 bytes
    signed char* labels = (ws_size >= need) ? (signed char*)d_ws : nullptr;

    dim3 grid((A_NUM + 255) / 256, B_NUM);
    targets_main_kernel<<<grid, 256, 0, stream>>>(annotations, anchors, out, labels);
    if (labels) {
        targets_fixup_kernel<<<dim3((B_NUM * A_NUM) / 256), 256, 0, stream>>>(labels, out);
    }
}

// Round 7
// 77.133 us; speedup vs baseline: 1.0327x; 1.0155x over previous
//
#include <hip/hip_runtime.h>

#define NUM_CLASSES 80
#define A_NUM 120000
#define B_NUM 8
#define N_BOX 64

typedef float f4 __attribute__((ext_vector_type(4)));

// R7: barrier-free, fence-free store-first K1 + sparse-fixup K2.
//
// R5/R6 lesson: __syncthreads() emits s_waitcnt vmcnt(0) before s_barrier,
// so ANY zero-stores issued before a barrier drain behind the global write
// backlog -> per-wave serialization. Fix: no barrier at all.
//  - Per-WAVE LDS staging: lane l loads box l, ds_writes its wave's region;
//    RAW is wave-internal (lgkmcnt, compiler-handled).
//  - All vmem LOADS (anchor + annotation) issue BEFORE the 20 zero-stores:
//    vmcnt is an in-order FIFO, so consuming the loads waits only for the
//    oldest entries (vmcnt(~20)) -> the stores never drain mid-kernel.
//  - One-hot "1.0" fixups deferred to K2; the dispatch boundary is the WAW
//    fence, at zero intra-kernel cost.
__global__ __launch_bounds__(256, 4) void targets_main_kernel(
    const float* __restrict__ annotations,  // (B, 64, 5)
    const float4* __restrict__ anchors4,    // (A, 4)
    float* __restrict__ out,                // cls | reg | states
    signed char* __restrict__ labels)       // (B*A) ws
{
#pragma clang fp contract(off)
    __shared__ float4 sbox[4][N_BOX];
    __shared__ float  sarea[4][N_BOX];
    __shared__ int    slab[4][N_BOX];

    const int tid  = threadIdx.x;
    const int wv   = tid >> 6;
    const int lane = tid & 63;
    const int b    = blockIdx.y;
    const int a0   = blockIdx.x * 256;
    const int aw0  = a0 + wv * 64;   // wave's anchor base (A_NUM % 64 == 0)
    const int a    = a0 + tid;
    if (aw0 >= A_NUM) return;        // whole wave valid or whole wave out

    // ---- 1. Issue all vmem LOADS first (anchor + this lane's box).
    const float4 anc = anchors4[a];
    const float* ann = annotations + ((size_t)b * N_BOX + lane) * 5;
    const float x0 = ann[0], y0 = ann[1], x1 = ann[2], y1 = ann[3];
    const float lb = ann[4];

    // ---- 2. Wave-local LDS staging (no barrier; lgkmcnt orders RAW).
    sbox[wv][lane]  = make_float4(x0, y0, x1, y1);
    sarea[wv][lane] = (x1 - x0) * (y1 - y0);   // same f32 ops as reference
    slab[wv][lane]  = (int)lb;

    // ---- 3. Fire-and-forget zero-fill of this wave's one-hot rows (20KB).
    // Issued after the loads -> nothing below ever waits on these stores.
    f4* const clsbase = (f4*)out + ((size_t)b * A_NUM + aw0) * 20;
    {
        const f4 z = {0.0f, 0.0f, 0.0f, 0.0f};
#pragma unroll
        for (int i = 0; i < 20; ++i)
            __builtin_nontemporal_store(z, &clsbase[i * 64 + lane]);
    }

    // ---- 4. argmax-IoU, numpy-exact (VALU + LDS broadcast reads only).
    const float wa = anc.z - anc.x;
    const float ha = anc.w - anc.y;
    const float area_a = wa * ha;

    float best_iou = -1.0f;
    int   best_j   = 0;
#pragma unroll 8
    for (int j = 0; j < N_BOX; ++j) {
        const float4 bx = sbox[wv][j];                // LDS broadcast
        const float ltx = fmaxf(anc.x, bx.x);
        const float lty = fmaxf(anc.y, bx.y);
        const float rbx = fminf(anc.z, bx.z);
        const float rby = fminf(anc.w, bx.w);
        const float w = fmaxf(rbx - ltx, 0.0f);
        const float h = fmaxf(rby - lty, 0.0f);
        const float inter = w * h;
        const float uni   = (area_a + sarea[wv][j]) - inter;  // no fma
        // union >= max(area) >= 1 (wh in [1,257]) so fmax(uni,1e-8) == uni.
        const float iou   = inter / uni;                      // IEEE div
        if (iou > best_iou) { best_iou = iou; best_j = j; }   // first-max wins
    }

    const bool positive = best_iou >= 0.5f;
    const bool ignore   = (best_iou > 0.4f) && !positive;
    const float state   = positive ? 1.0f : (ignore ? -1.0f : 0.0f);

    const float4 gt = sbox[wv][best_j];
    f4 reg;
    reg.x = ((gt.x - anc.x) / wa) / 0.2f;
    reg.y = ((gt.y - anc.y) / ha) / 0.2f;
    reg.z = ((gt.z - anc.z) / wa) / 0.2f;
    reg.w = ((gt.w - anc.w) / ha) / 0.2f;

    const size_t CLS = (size_t)B_NUM * A_NUM * NUM_CLASSES;
    const size_t REG = (size_t)B_NUM * A_NUM * 4;
    f4* regout = (f4*)(out + CLS);
    __builtin_nontemporal_store(reg, &regout[(size_t)b * A_NUM + a]);
    __builtin_nontemporal_store(state, &out[CLS + REG + (size_t)b * A_NUM + a]);
    labels[(size_t)b * A_NUM + a] =
        positive ? (signed char)slab[wv][best_j] : (signed char)-1;
}

// K2: sparse one-hot fixup. 3750*256 == 960000 exactly.
__global__ __launch_bounds__(256) void targets_fixup_kernel(
    const signed char* __restrict__ labels,
    float* __restrict__ out)
{
    const int idx = blockIdx.x * 256 + threadIdx.x;   // = b*A + a
    const int lab = labels[idx];
    if (lab >= 0)
        out[(size_t)idx * NUM_CLASSES + lab] = 1.0f;
}

// Fallback (ws too small): proven R2 fused kernel (60.7us).
__global__ __launch_bounds__(256, 4) void targets_fused_kernel(
    const float* __restrict__ annotations,
    const float4* __restrict__ anchors4,
    float* __restrict__ out)
{
#pragma clang fp contract(off)
    __shared__ float4 sbox[N_BOX];
    __shared__ float  sarea[N_BOX];
    __shared__ int    slab[N_BOX];
    __shared__ int    scls[256];

    const int tid  = threadIdx.x;
    const int wv   = tid >> 6;
    const int lane = tid & 63;
    const int b    = blockIdx.y;
    const int a0   = blockIdx.x * 256;
    const int aw0  = a0 + wv * 64;
    const int a    = a0 + tid;

    if (tid < N_BOX) {
        const float* ann = annotations + ((size_t)b * N_BOX + tid) * 5;
        const float x0 = ann[0], y0 = ann[1], x1 = ann[2], y1 = ann[3];
        sbox[tid]  = make_float4(x0, y0, x1, y1);
        sarea[tid] = (x1 - x0) * (y1 - y0);
        slab[tid]  = (int)ann[4];
    }
    __syncthreads();
    if (aw0 >= A_NUM) return;

    const float4 anc = anchors4[a];
    const float wa = anc.z - anc.x;
    const float ha = anc.w - anc.y;
    const float area_a = wa * ha;

    float best_iou = -1.0f;
    int   best_j   = 0;
#pragma unroll 8
    for (int j = 0; j < N_BOX; ++j) {
        const float4 bx = sbox[j];
        const float ltx = fmaxf(anc.x, bx.x);
        const float lty = fmaxf(anc.y, bx.y);
        const float rbx = fminf(anc.z, bx.z);
        const float rby = fminf(anc.w, bx.w);
        const float w = fmaxf(rbx - ltx, 0.0f);
        const float h = fmaxf(rby - lty, 0.0f);
        const float inter = w * h;
        const float uni   = (area_a + sarea[j]) - inter;
        const float iou   = inter / uni;
        if (iou > best_iou) { best_iou = iou; best_j = j; }
    }

    const bool positive = best_iou >= 0.5f;
    const bool ignore   = (best_iou > 0.4f) && !positive;
    const float state   = positive ? 1.0f : (ignore ? -1.0f : 0.0f);

    const float4 gt = sbox[best_j];
    f4 reg;
    reg.x = ((gt.x - anc.x) / wa) / 0.2f;
    reg.y = ((gt.y - anc.y) / ha) / 0.2f;
    reg.z = ((gt.z - anc.z) / wa) / 0.2f;
    reg.w = ((gt.w - anc.w) / ha) / 0.2f;

    const size_t CLS = (size_t)B_NUM * A_NUM * NUM_CLASSES;
    const size_t REG = (size_t)B_NUM * A_NUM * 4;
    f4* regout = (f4*)(out + CLS);
    __builtin_nontemporal_store(reg, &regout[(size_t)b * A_NUM + a]);
    __builtin_nontemporal_store(state, &out[CLS + REG + (size_t)b * A_NUM + a]);

    scls[tid] = positive ? slab[best_j] : -1;
    f4* clsout = (f4*)out + ((size_t)b * A_NUM + aw0) * 20;
#pragma unroll
    for (int i = 0; i < 20; ++i) {
        const int pos = i * 64 + lane;
        const int al  = pos / 20;
        const int q   = pos - al * 20;
        const int lab = scls[wv * 64 + al];
        const int c0  = q * 4;
        f4 v;
        v.x = (lab == c0    ) ? 1.0f : 0.0f;
        v.y = (lab == c0 + 1) ? 1.0f : 0.0f;
        v.z = (lab == c0 + 2) ? 1.0f : 0.0f;
        v.w = (lab == c0 + 3) ? 1.0f : 0.0f;
        __builtin_nontemporal_store(v, &clsout[pos]);
    }
}

extern "C" void kernel_launch(void* const* d_in, const int* in_sizes, int n_in,
                              void* d_out, int out_size, void* d_ws, size_t ws_size,
                              hipStream_t stream) {
    const float*  annotations = (const float*)d_in[0];   // (8, 64, 5)
    const float4* anchors     = (const float4*)d_in[1];  // (120000, 4)
    float* out = (float*)d_out;

    const size_t need = (size_t)B_NUM * A_NUM;           // 960000 bytes
    dim3 grid((A_NUM + 255) / 256, B_NUM);
    if (ws_size >= need) {
        signed char* labels = (signed char*)d_ws;
        targets_main_kernel<<<grid, 256, 0, stream>>>(annotations, anchors, out, labels);
        targets_fixup_kernel<<<dim3((B_NUM * A_NUM) / 256), 256, 0, stream>>>(labels, out);
    } else {
        targets_fused_kernel<<<grid, 256, 0, stream>>>(annotations, anchors, out);
    }
}